// Round 3
// baseline (398.447 us; speedup 1.0000x reference)
//
#include <hip/hip_runtime.h>
#include <hip/hip_bf16.h>
#include <cstdint>
#include <cstddef>

#define N_TOK 65536
#define DIM 128
#define HID 256
#define NE 32
#define TOPK 2

typedef __bf16 bf16x8 __attribute__((ext_vector_type(8)));
typedef float f32x4 __attribute__((ext_vector_type(4)));

__device__ __forceinline__ unsigned short f2bf(float f) {
  unsigned u = __builtin_bit_cast(unsigned, f);
  u += 0x7fffu + ((u >> 16) & 1u);   // round-to-nearest-even
  return (unsigned short)(u >> 16);
}
__device__ __forceinline__ float bf2f(unsigned s) {
  return __builtin_bit_cast(float, s << 16);
}

// ---------------- fallback-only: zero out ----------------
__global__ void k_zero_out(float* __restrict__ out) {
  int t = blockIdx.x * 256 + threadIdx.x;
  float4 z = make_float4(0.f, 0.f, 0.f, 0.f);
  float4* o4 = (float4*)out;
  o4[t] = z;
  o4[t + 1048576] = z;
}

// ---------------- convert + transpose weights to bf16 (K-chunk-tiled) + fp64 Wr^T ----------------
// w1t[e]: element (h,d) at (d>>5)*8192 + h*32 + (d&31)
// w2t[e]: element (d,h) at (h>>5)*4096 + d*32 + (h&31)
__global__ void k_weights(const float* __restrict__ W1, const float* __restrict__ W2,
                          const float* __restrict__ Wr,
                          unsigned short* __restrict__ w1t, unsigned short* __restrict__ w2t,
                          double* __restrict__ wrt64, float* __restrict__ ws32) {
  int b = blockIdx.x;
  if (b == 512) {   // Wr transpose to fp64 column-major [e][d]
#pragma unroll
    for (int j = 0; j < 16; ++j) {
      int idx = j * 256 + threadIdx.x;
      int e = idx >> 7, d = idx & 127;
      wrt64[idx] = (double)Wr[d * NE + e];
    }
    return;
  }
  if (b == 0 && threadIdx.x < 96) ws32[threadIdx.x] = 0.f;
  const float* in;
  unsigned short* out;
  int K, r0, c0;
  if (b < 256) {
    int e = b >> 3, tt = b & 7;
    in = W1 + (size_t)e * DIM * HID;   // [d][h] 128x256
    out = w1t + (size_t)e * DIM * HID;
    K = HID;
    r0 = (tt >> 2) * 64; c0 = (tt & 3) * 64;   // r=d, c=h
  } else {
    b -= 256;
    int e = b >> 3, tt = b & 7;
    in = W2 + (size_t)e * HID * DIM;   // [h][d] 256x128
    out = w2t + (size_t)e * HID * DIM;
    K = DIM;
    r0 = (tt >> 1) * 64; c0 = (tt & 1) * 64;   // r=h, c=d
  }
  __shared__ float tile[64][65];
  int t2 = threadIdx.x;
  int r = t2 >> 2, cs = (t2 & 3) * 16;
  const float* src = in + (size_t)(r0 + r) * K + c0 + cs;
#pragma unroll
  for (int j = 0; j < 4; ++j) {
    float4 v = *(const float4*)(src + j * 4);
    tile[r][cs + j * 4 + 0] = v.x;
    tile[r][cs + j * 4 + 1] = v.y;
    tile[r][cs + j * 4 + 2] = v.z;
    tile[r][cs + j * 4 + 3] = v.w;
  }
  __syncthreads();
#pragma unroll
  for (int p = 0; p < 2; ++p) {
    int orow = p * 32 + (t2 >> 3);        // col index within tile
    int oc8 = (t2 & 7) * 8;
    int rr = r0 + oc8;                    // row index, 8 consecutive
    unsigned pk[4];
#pragma unroll
    for (int q = 0; q < 4; ++q) {
      unsigned lo = f2bf(tile[oc8 + 2 * q][orow]);
      unsigned hi = f2bf(tile[oc8 + 2 * q + 1][orow]);
      pk[q] = lo | (hi << 16);
    }
    uint4 u;
    u.x = pk[0]; u.y = pk[1]; u.z = pk[2]; u.w = pk[3];
    size_t addr = (size_t)(rr >> 5) * (K * 32) + (size_t)(c0 + orow) * 32 + (rr & 31);
    *(uint4*)(out + addr) = u;
  }
}

// ---------------- router: fp64 logits, softmax top-2 ----------------
__global__ __launch_bounds__(256) void k_router(const float* __restrict__ x,
                                                const double* __restrict__ wrt64,
                                                const float* __restrict__ br,
                                                int* __restrict__ top_idx,
                                                float* __restrict__ top_val) {
  __shared__ __align__(16) double xs64[8][128];
  int t = threadIdx.x;
  int tok0 = blockIdx.x * 8;
  {
    int tk = t >> 5;           // 0..7
    int d0 = t & 31;
    const float* xr = x + (size_t)(tok0 + tk) * DIM;
#pragma unroll
    for (int j = 0; j < 4; ++j)
      xs64[tk][d0 + j * 32] = (double)xr[d0 + j * 32];
  }
  __syncthreads();
  int lt = t & 31;
  int tok = t >> 5;
  const double* wcol = wrt64 + lt * DIM;
  const double* xrow = xs64[tok];
  double a0 = 0, a1 = 0, a2 = 0, a3 = 0;
#pragma unroll 4
  for (int d = 0; d < DIM; d += 4) {
    double2 w0 = *(const double2*)(wcol + d);
    double2 w1 = *(const double2*)(wcol + d + 2);
    double2 x0 = *(const double2*)(xrow + d);       // LDS broadcast (free)
    double2 x1 = *(const double2*)(xrow + d + 2);
    a0 = fma(x0.x, w0.x, a0);
    a1 = fma(x0.y, w0.y, a1);
    a2 = fma(x1.x, w1.x, a2);
    a3 = fma(x1.y, w1.y, a3);
  }
  double lv = ((a0 + a1) + (a2 + a3)) + (double)br[lt];

  double v1 = lv; int i1 = lt;
#pragma unroll
  for (int off = 16; off > 0; off >>= 1) {
    double ov = __shfl_xor(v1, off, 32);
    int oi = __shfl_xor(i1, off, 32);
    if (ov > v1 || (ov == v1 && oi < i1)) { v1 = ov; i1 = oi; }
  }
  double lv2 = (lt == i1) ? -1.0e300 : lv;
  double v2 = lv2; int i2 = lt;
#pragma unroll
  for (int off = 16; off > 0; off >>= 1) {
    double ov = __shfl_xor(v2, off, 32);
    int oi = __shfl_xor(i2, off, 32);
    if (ov > v2 || (ov == v2 && oi < i2)) { v2 = ov; i2 = oi; }
  }
  float p = expf((float)(lv - v1));
  float s = p;
#pragma unroll
  for (int off = 16; off > 0; off >>= 1) s += __shfl_xor(s, off, 32);
  if (lt == 0) {
    int n = tok0 + tok;
    float g1 = 1.0f / s;
    float g2 = expf((float)(v2 - v1)) / s;
    top_idx[n * 2 + 0] = i1;
    top_idx[n * 2 + 1] = i2;
    top_val[n * 2 + 0] = g1;
    top_val[n * 2 + 1] = g2;
  }
}

// ---------------- histogram: counts + importance ----------------
__global__ void k_hist(const int* __restrict__ top_idx, const float* __restrict__ top_val,
                       int* __restrict__ counts, float* __restrict__ importance) {
  __shared__ int hc[NE];
  __shared__ float hf[NE];
  int t = threadIdx.x;
  if (t < NE) { hc[t] = 0; hf[t] = 0.f; }
  __syncthreads();
#pragma unroll
  for (int j = 0; j < 2; ++j) {
    int i = (j * 256 + blockIdx.x) * 256 + t;
    int e = top_idx[i];
    atomicAdd(&hc[e], 1);
    atomicAdd(&hf[e], top_val[i]);
  }
  __syncthreads();
  if (t < NE) {
    atomicAdd(&counts[t], hc[t]);
    atomicAdd(&importance[t], hf[t]);
  }
}

// ---------------- padded scan + load-balancing loss ----------------
__global__ void k_scan_loss(const int* __restrict__ counts, const float* __restrict__ importance,
                            int* __restrict__ offsets, float* __restrict__ out_loss) {
  int t = threadIdx.x;
  if (t < NE) {
    int pc = (counts[t] + 63) & ~63;
    int sc = pc;
#pragma unroll
    for (int off = 1; off < 32; off <<= 1) {
      int ov = __shfl_up(sc, off, 32);
      if (t >= off) sc += ov;
    }
    offsets[t] = sc - pc;
    if (t == NE - 1) offsets[NE] = sc;

    float imp = importance[t];
    float ssum = imp;
#pragma unroll
    for (int off = 16; off > 0; off >>= 1) ssum += __shfl_xor(ssum, off, 32);
    float mean = ssum / 32.0f;
    float dlt = imp - mean;
    float v = dlt * dlt;
#pragma unroll
    for (int off = 16; off > 0; off >>= 1) v += __shfl_xor(v, off, 32);
    float var = v / 31.0f;
    if (t == 0) *out_loss = var / (mean * mean + 1e-9f);
  }
}

// ---------------- scatter into per-expert lists (+ inverse map) ----------------
__global__ void k_scatter(const int* __restrict__ top_idx, const float* __restrict__ top_val,
                          const int* __restrict__ offsets, int* __restrict__ cursors,
                          int* __restrict__ perm, float* __restrict__ gatev,
                          int* __restrict__ inv) {
  __shared__ int hist[NE], base[NE], cur[NE];
  int t = threadIdx.x;
  if (t < NE) { hist[t] = 0; cur[t] = 0; }
  __syncthreads();
#pragma unroll
  for (int j = 0; j < 4; ++j) {
    int i = blockIdx.x * 1024 + j * 256 + t;
    atomicAdd(&hist[top_idx[i]], 1);
  }
  __syncthreads();
  if (t < NE) base[t] = atomicAdd(&cursors[t], hist[t]);
  __syncthreads();
#pragma unroll
  for (int j = 0; j < 4; ++j) {
    int i = blockIdx.x * 1024 + j * 256 + t;
    int e = top_idx[i];
    int p = atomicAdd(&cur[e], 1);
    int pos = offsets[e] + base[e] + p;
    perm[pos] = i >> 1;
    gatev[pos] = top_val[i];
    inv[i] = pos;
  }
}

// ---------------- fused expert GEMM: 64 tokens x 1 expert per block ----------------
// Weights held in VGPRs (direct global->reg fragment loads); only 2 barriers.
// YB=1: write y = g*(O+b2) bf16 to ybuf[pos][128]; YB=0: atomicAdd into out.
template <int YB>
__global__ __launch_bounds__(256, 2) void k_expert(
    const float* __restrict__ x, const unsigned short* __restrict__ w1t,
    const unsigned short* __restrict__ w2t, const float* __restrict__ b1,
    const float* __restrict__ b2, const int* __restrict__ offsets,
    const int* __restrict__ counts, const int* __restrict__ perm,
    const float* __restrict__ gatev, unsigned short* __restrict__ ybuf,
    float* __restrict__ out) {
  __shared__ __align__(16) unsigned char smem[49152];
  unsigned char* xa = smem;                 // 16 KB: [c 0..15][row 0..63][16B]
  unsigned char* ha = smem + 16384;         // 32 KB: [c 0..31][row 0..63][16B]

  int slot0 = blockIdx.x * 64;
  if (slot0 >= offsets[NE]) return;
  int e = 0;
#pragma unroll
  for (int i = 1; i < NE; ++i)
    if (slot0 >= offsets[i]) e = i;
  int cnt = counts[e];
  int local0 = slot0 - offsets[e];
  int nvalid = min(64, cnt - local0);

  int t = threadIdx.x;
  int w = t >> 6;
  int l = t & 63;
  int quad = l >> 4;
  int l15 = l & 15;

  // ---- W1 fragments -> VGPRs (coalesced 1 KB/wave per fragment, L2-resident) ----
  const unsigned short* w1e = w1t + (size_t)e * DIM * HID;
  bf16x8 w1f[4][4];   // [kc][jt]
#pragma unroll
  for (int kc = 0; kc < 4; ++kc)
#pragma unroll
    for (int jt = 0; jt < 4; ++jt)
      w1f[kc][jt] = *(const bf16x8*)(w1e + kc * 8192 + (w * 64 + jt * 16 + l15) * 32 + quad * 8);

  // ---- stage x rows into LDS (gather + fp32->bf16) ----
  {
    int r = t & 63;
    int half = t >> 6;
    unsigned pk[16];
    if (r < nvalid) {
      int token = perm[slot0 + r];
      const float* src = x + (size_t)token * DIM + half * 32;
#pragma unroll
      for (int q = 0; q < 8; ++q) {
        float4 v = ((const float4*)src)[q];
        pk[q * 2 + 0] = (unsigned)f2bf(v.x) | ((unsigned)f2bf(v.y) << 16);
        pk[q * 2 + 1] = (unsigned)f2bf(v.z) | ((unsigned)f2bf(v.w) << 16);
      }
    } else {
#pragma unroll
      for (int q = 0; q < 16; ++q) pk[q] = 0u;
    }
#pragma unroll
    for (int cc = 0; cc < 4; ++cc) {
      uint4 u;
      u.x = pk[cc * 4 + 0]; u.y = pk[cc * 4 + 1]; u.z = pk[cc * 4 + 2]; u.w = pk[cc * 4 + 3];
      *(uint4*)(xa + (half * 4 + cc) * 1024 + r * 16) = u;
    }
  }
  __syncthreads();

  // ---- stage 1: H = relu(X @ W1e + b1e), wave w owns j in [w*64, w*64+64) ----
  f32x4 acc[4][4];
#pragma unroll
  for (int a = 0; a < 4; ++a)
#pragma unroll
    for (int b = 0; b < 4; ++b) {
      f32x4 z = {0.f, 0.f, 0.f, 0.f};
      acc[a][b] = z;
    }
#pragma unroll
  for (int kc = 0; kc < 4; ++kc) {
    bf16x8 af[4];
#pragma unroll
    for (int rt = 0; rt < 4; ++rt)
      af[rt] = *(const bf16x8*)(xa + (kc * 4 + quad) * 1024 + (rt * 16 + l15) * 16);
#pragma unroll
    for (int rt = 0; rt < 4; ++rt)
#pragma unroll
      for (int jt = 0; jt < 4; ++jt)
        acc[rt][jt] = __builtin_amdgcn_mfma_f32_16x16x32_bf16(af[rt], w1f[kc][jt], acc[rt][jt], 0, 0, 0);
  }

  // ---- W2 fragments -> VGPRs (independent; overlaps with H write) ----
  const unsigned short* w2e = w2t + (size_t)e * HID * DIM;
  bf16x8 w2f[8][2];   // [hc][jt]
#pragma unroll
  for (int hc = 0; hc < 8; ++hc)
#pragma unroll
    for (int jt = 0; jt < 2; ++jt)
      w2f[hc][jt] = *(const bf16x8*)(w2e + hc * 4096 + (w * 32 + jt * 16 + l15) * 32 + quad * 8);

  // ---- bias + relu + write H to LDS in A-layout (bf16) ----
  const float* b1e = b1 + e * HID;
#pragma unroll
  for (int jt = 0; jt < 4; ++jt) {
    int col = w * 64 + jt * 16 + l15;
    float b1v = b1e[col];
    int c = col >> 3;
    int byteoff = (col & 7) * 2;
#pragma unroll
    for (int rt = 0; rt < 4; ++rt) {
#pragma unroll
      for (int r = 0; r < 4; ++r) {
        int tokrow = rt * 16 + quad * 4 + r;
        float v = acc[rt][jt][r] + b1v;
        v = v > 0.f ? v : 0.f;
        *(unsigned short*)(ha + c * 1024 + tokrow * 16 + byteoff) = f2bf(v);
      }
    }
  }
  __syncthreads();

  // ---- stage 2: O = H @ W2e, wave w owns d in [w*32, w*32+32) ----
  f32x4 accc[4][2];
#pragma unroll
  for (int a = 0; a < 4; ++a)
#pragma unroll
    for (int b = 0; b < 2; ++b) {
      f32x4 z = {0.f, 0.f, 0.f, 0.f};
      accc[a][b] = z;
    }
#pragma unroll
  for (int hc = 0; hc < 8; ++hc) {
    bf16x8 ah[4];
#pragma unroll
    for (int rt = 0; rt < 4; ++rt)
      ah[rt] = *(const bf16x8*)(ha + (hc * 4 + quad) * 1024 + (rt * 16 + l15) * 16);
#pragma unroll
    for (int rt = 0; rt < 4; ++rt)
#pragma unroll
      for (int jt = 0; jt < 2; ++jt)
        accc[rt][jt] = __builtin_amdgcn_mfma_f32_16x16x32_bf16(ah[rt], w2f[hc][jt], accc[rt][jt], 0, 0, 0);
  }

  // ---- epilogue ----
  int dbase = w * 32;
  float b2v0 = b2[e * DIM + dbase + l15];
  float b2v1 = b2[e * DIM + dbase + 16 + l15];
#pragma unroll
  for (int rt = 0; rt < 4; ++rt) {
#pragma unroll
    for (int r = 0; r < 4; ++r) {
      int tokrow = rt * 16 + quad * 4 + r;
      if (tokrow < nvalid) {
        int pos = slot0 + tokrow;
        float g = gatev[pos];
        if (YB) {
          unsigned short* yrow = ybuf + (size_t)pos * DIM + dbase;
          yrow[l15] = f2bf(g * (accc[rt][0][r] + b2v0));
          yrow[16 + l15] = f2bf(g * (accc[rt][1][r] + b2v1));
        } else {
          int token = perm[pos];
          float* orow = out + (size_t)token * DIM + dbase;
          atomicAdd(&orow[l15], g * (accc[rt][0][r] + b2v0));
          atomicAdd(&orow[16 + l15], g * (accc[rt][1][r] + b2v1));
        }
      }
    }
  }
}

// ---------------- combine: out[n] = y[inv[2n]] + y[inv[2n+1]] ----------------
__global__ __launch_bounds__(256) void k_combine(const unsigned short* __restrict__ ybuf,
                                                 const int* __restrict__ inv,
                                                 float* __restrict__ out) {
  int t = threadIdx.x;
  int n = blockIdx.x * 16 + (t >> 4);
  int lane = t & 15;
  int p0 = inv[n * 2 + 0];
  int p1 = inv[n * 2 + 1];
  uint4 a = *((const uint4*)(ybuf + (size_t)p0 * DIM) + lane);
  uint4 b = *((const uint4*)(ybuf + (size_t)p1 * DIM) + lane);
  unsigned av[4] = {a.x, a.y, a.z, a.w}, bv[4] = {b.x, b.y, b.z, b.w};
  float r[8];
#pragma unroll
  for (int q = 0; q < 4; ++q) {
    r[q * 2 + 0] = bf2f(av[q] & 0xffffu) + bf2f(bv[q] & 0xffffu);
    r[q * 2 + 1] = bf2f(av[q] >> 16) + bf2f(bv[q] >> 16);
  }
  float* orow = out + (size_t)n * DIM + lane * 8;
  float4 w0 = {r[0], r[1], r[2], r[3]}, w1 = {r[4], r[5], r[6], r[7]};
  ((float4*)orow)[0] = w0;
  ((float4*)orow)[1] = w1;
}

extern "C" void kernel_launch(void* const* d_in, const int* in_sizes, int n_in,
                              void* d_out, int out_size, void* d_ws, size_t ws_size,
                              hipStream_t stream) {
  const float* x  = (const float*)d_in[0];
  const float* W1 = (const float*)d_in[1];
  const float* b1 = (const float*)d_in[2];
  const float* W2 = (const float*)d_in[3];
  const float* b2 = (const float*)d_in[4];
  const float* Wr = (const float*)d_in[5];
  const float* br = (const float*)d_in[6];
  float* out = (float*)d_out;

  char* ws = (char*)d_ws;
  float* importance   = (float*)(ws + 0);       // 32 f
  int*   counts       = (int*)(ws + 128);       // 32 i
  int*   cursors      = (int*)(ws + 256);       // 32 i
  int*   offsets      = (int*)(ws + 384);       // 33 i
  int*   top_idx      = (int*)(ws + 1024);              // 131072 i
  float* top_val      = (float*)(ws + 525312);          // 131072 f
  int*   perm         = (int*)(ws + 1049600);           // 133120 i
  float* gatev        = (float*)(ws + 1582080);         // 133120 f
  int*   inv          = (int*)(ws + 2114560);           // 131072 i -> 2638848
  unsigned short* w1t = (unsigned short*)(ws + 2638848);            // 2 MB -> 4736000
  unsigned short* w2t = (unsigned short*)(ws + 4736000);            // 2 MB -> 6833152
  unsigned short* ybuf = (unsigned short*)(ws + 6833152);           // 34078720 -> 40911872
  double* wrt64 = (double*)(ws + 6833152);   // 32 KB, aliases ybuf head (dead before k_expert)
  const size_t NEEDED = 40911872;
  bool use_ybuf = ws_size >= NEEDED;

  hipLaunchKernelGGL(k_weights, dim3(513), dim3(256), 0, stream, W1, W2, Wr, w1t, w2t, wrt64,
                     (float*)ws);
  hipLaunchKernelGGL(k_router, dim3(8192), dim3(256), 0, stream, x, wrt64, br, top_idx, top_val);
  hipLaunchKernelGGL(k_hist, dim3(256), dim3(256), 0, stream, top_idx, top_val, counts, importance);
  hipLaunchKernelGGL(k_scan_loss, dim3(1), dim3(64), 0, stream, counts, importance, offsets,
                     out + (size_t)N_TOK * DIM);
  hipLaunchKernelGGL(k_scatter, dim3(128), dim3(256), 0, stream, top_idx, top_val, offsets,
                     cursors, perm, gatev, inv);
  if (use_ybuf) {
    hipLaunchKernelGGL((k_expert<1>), dim3(2080), dim3(256), 0, stream, x, w1t, w2t, b1, b2,
                       offsets, counts, perm, gatev, ybuf, out);
    hipLaunchKernelGGL(k_combine, dim3(4096), dim3(256), 0, stream, ybuf, inv, out);
  } else {
    hipLaunchKernelGGL(k_zero_out, dim3(4096), dim3(256), 0, stream, out);
    hipLaunchKernelGGL((k_expert<0>), dim3(2080), dim3(256), 0, stream, x, w1t, w2t, b1, b2,
                       offsets, counts, perm, gatev, ybuf, out);
  }
}

// Round 5
// 216.419 us; speedup vs baseline: 1.8411x; 1.8411x over previous
//
#include <hip/hip_runtime.h>
#include <hip/hip_bf16.h>
#include <cstdint>
#include <cstddef>

#define N_TOK 65536
#define DIM 128
#define HID 256
#define NE 32
#define TOPK 2

typedef __bf16 bf16x8 __attribute__((ext_vector_type(8)));
typedef float f32x4 __attribute__((ext_vector_type(4)));
typedef unsigned uint4v __attribute__((ext_vector_type(4)));

__device__ __forceinline__ unsigned short f2bf(float f) {
  unsigned u = __builtin_bit_cast(unsigned, f);
  u += 0x7fffu + ((u >> 16) & 1u);   // round-to-nearest-even
  return (unsigned short)(u >> 16);
}
__device__ __forceinline__ float bf2f(unsigned s) {
  return __builtin_bit_cast(float, s << 16);
}
// truncation split: f = hi + lo + O(2^-14 |f|); packs two values' shorts into one uint.
// returns {hi_pair, lo_pair}
__device__ __forceinline__ uint2 split2(float f0, float f1) {
  unsigned u0 = __builtin_bit_cast(unsigned, f0);
  unsigned u1 = __builtin_bit_cast(unsigned, f1);
  unsigned hi = (u0 >> 16) | (u1 & 0xffff0000u);
  float r0 = f0 - __builtin_bit_cast(float, u0 & 0xffff0000u);
  float r1 = f1 - __builtin_bit_cast(float, u1 & 0xffff0000u);
  unsigned lo = (__builtin_bit_cast(unsigned, r0) >> 16) |
                (__builtin_bit_cast(unsigned, r1) & 0xffff0000u);
  uint2 ret; ret.x = hi; ret.y = lo;
  return ret;
}

// ---------------- fallback-only: zero out ----------------
__global__ void k_zero_out(float* __restrict__ out) {
  int t = blockIdx.x * 256 + threadIdx.x;
  float4 z = make_float4(0.f, 0.f, 0.f, 0.f);
  float4* o4 = (float4*)out;
  o4[t] = z;
  o4[t + 1048576] = z;
}

// ---------------- convert + transpose weights (K-chunk-tiled) + router weight prep ----------------
// w1t[e]: element (h,d) at (d>>5)*8192 + h*32 + (d&31)
// w2t[e]: element (d,h) at (h>>5)*4096 + d*32 + (h&31)
// wrt64: fp64 Wr^T column-major [e][d]
// wrb: bf16 hi/lo B-fragments of Wr for mfma_16x16x32: [s][nt][kc][q][n][j], 16384 shorts
__global__ void k_weights(const float* __restrict__ W1, const float* __restrict__ W2,
                          const float* __restrict__ Wr,
                          unsigned short* __restrict__ w1t, unsigned short* __restrict__ w2t,
                          double* __restrict__ wrt64, unsigned short* __restrict__ wrb,
                          float* __restrict__ ws32, int* __restrict__ n_suspect) {
  int b = blockIdx.x;
  if (b == 512) {
    if (threadIdx.x == 0) *n_suspect = 0;
#pragma unroll
    for (int j = 0; j < 16; ++j) {    // fp64 Wr^T
      int idx = j * 256 + threadIdx.x;
      int e = idx >> 7, d = idx & 127;
      wrt64[idx] = (double)Wr[d * NE + e];
    }
#pragma unroll
    for (int j = 0; j < 16; ++j) {    // bf16 hi/lo B-fragments
      int idx = j * 256 + threadIdx.x;
      int k = idx >> 5, e = idx & 31;
      float w = Wr[k * NE + e];
      unsigned u = __builtin_bit_cast(unsigned, w);
      unsigned short hs = (unsigned short)(u >> 16);
      float r = w - __builtin_bit_cast(float, u & 0xffff0000u);
      unsigned short ls = (unsigned short)(__builtin_bit_cast(unsigned, r) >> 16);
      int nt = e >> 4, n = e & 15, kc = k >> 5, q = (k >> 3) & 3, jj = k & 7;
      size_t base = ((((size_t)nt * 4 + kc) * 4 + q) * 16 + n) * 8 + jj;
      wrb[base] = hs;
      wrb[8192 + base] = ls;
    }
    return;
  }
  if (b == 0 && threadIdx.x < 96) ws32[threadIdx.x] = 0.f;
  const float* in;
  unsigned short* out;
  int K, r0, c0;
  if (b < 256) {
    int e = b >> 3, tt = b & 7;
    in = W1 + (size_t)e * DIM * HID;   // [d][h] 128x256
    out = w1t + (size_t)e * DIM * HID;
    K = HID;
    r0 = (tt >> 2) * 64; c0 = (tt & 3) * 64;
  } else {
    b -= 256;
    int e = b >> 3, tt = b & 7;
    in = W2 + (size_t)e * HID * DIM;   // [h][d] 256x128
    out = w2t + (size_t)e * HID * DIM;
    K = DIM;
    r0 = (tt >> 1) * 64; c0 = (tt & 1) * 64;
  }
  __shared__ float tile[64][65];
  int t2 = threadIdx.x;
  int r = t2 >> 2, cs = (t2 & 3) * 16;
  const float* src = in + (size_t)(r0 + r) * K + c0 + cs;
#pragma unroll
  for (int j = 0; j < 4; ++j) {
    float4 v = *(const float4*)(src + j * 4);
    tile[r][cs + j * 4 + 0] = v.x;
    tile[r][cs + j * 4 + 1] = v.y;
    tile[r][cs + j * 4 + 2] = v.z;
    tile[r][cs + j * 4 + 3] = v.w;
  }
  __syncthreads();
#pragma unroll
  for (int p = 0; p < 2; ++p) {
    int orow = p * 32 + (t2 >> 3);
    int oc8 = (t2 & 7) * 8;
    int rr = r0 + oc8;
    unsigned pk[4];
#pragma unroll
    for (int q = 0; q < 4; ++q) {
      unsigned lo = f2bf(tile[oc8 + 2 * q][orow]);
      unsigned hi = f2bf(tile[oc8 + 2 * q + 1][orow]);
      pk[q] = lo | (hi << 16);
    }
    uint4 u;
    u.x = pk[0]; u.y = pk[1]; u.z = pk[2]; u.w = pk[3];
    size_t addr = (size_t)(rr >> 5) * (K * 32) + (size_t)(c0 + orow) * 32 + (rr & 31);
    *(uint4*)(out + addr) = u;
  }
}

// ---------------- router: MFMA split-precision logits + in-register top-2 ----------------
__global__ __launch_bounds__(256) void k_router(
    const float* __restrict__ x, const unsigned short* __restrict__ wrb,
    const float* __restrict__ br, int* __restrict__ top_idx, float* __restrict__ top_val,
    int* __restrict__ suspects, int* __restrict__ n_suspect) {
  int t = threadIdx.x;
  int w = t >> 6, l = t & 63, quad = l >> 4, l15 = l & 15;
  int tok0 = blockIdx.x * 256 + w * 64;

  // B fragments (L1-hot, 32 KB total): [s hi/lo][nt][kc]
  bf16x8 bfr[2][2][4];
#pragma unroll
  for (int s = 0; s < 2; ++s)
#pragma unroll
    for (int nt = 0; nt < 2; ++nt)
#pragma unroll
      for (int kc = 0; kc < 4; ++kc)
        bfr[s][nt][kc] = *(const bf16x8*)(wrb + s * 8192 +
                          ((((size_t)nt * 4 + kc) * 4 + quad) * 16 + l15) * 8);

  f32x4 acc[4][2];
#pragma unroll
  for (int a = 0; a < 4; ++a)
#pragma unroll
    for (int b = 0; b < 2; ++b) {
      f32x4 z = {0.f, 0.f, 0.f, 0.f};
      acc[a][b] = z;
    }

#pragma unroll
  for (int mt = 0; mt < 4; ++mt) {
    const float* xp = x + (size_t)(tok0 + mt * 16 + l15) * DIM + quad * 8;
    float4 va[4][2];
#pragma unroll
    for (int kc = 0; kc < 4; ++kc) {
      const float4* p = (const float4*)(xp + kc * 32);
      va[kc][0] = p[0];
      va[kc][1] = p[1];
    }
#pragma unroll
    for (int kc = 0; kc < 4; ++kc) {
      uint2 s0 = split2(va[kc][0].x, va[kc][0].y);
      uint2 s1 = split2(va[kc][0].z, va[kc][0].w);
      uint2 s2 = split2(va[kc][1].x, va[kc][1].y);
      uint2 s3 = split2(va[kc][1].z, va[kc][1].w);
      uint4v hu, lu;
      hu[0] = s0.x; lu[0] = s0.y;
      hu[1] = s1.x; lu[1] = s1.y;
      hu[2] = s2.x; lu[2] = s2.y;
      hu[3] = s3.x; lu[3] = s3.y;
      bf16x8 ahi = __builtin_bit_cast(bf16x8, hu);
      bf16x8 alo = __builtin_bit_cast(bf16x8, lu);
#pragma unroll
      for (int nt = 0; nt < 2; ++nt) {
        acc[mt][nt] = __builtin_amdgcn_mfma_f32_16x16x32_bf16(ahi, bfr[0][nt][kc], acc[mt][nt], 0, 0, 0);
        acc[mt][nt] = __builtin_amdgcn_mfma_f32_16x16x32_bf16(ahi, bfr[1][nt][kc], acc[mt][nt], 0, 0, 0);
        acc[mt][nt] = __builtin_amdgcn_mfma_f32_16x16x32_bf16(alo, bfr[0][nt][kc], acc[mt][nt], 0, 0, 0);
      }
    }
  }

  float brv0 = br[l15], brv1 = br[16 + l15];
  const float NINF = -3.0e38f;
#pragma unroll
  for (int mt = 0; mt < 4; ++mt) {
#pragma unroll
    for (int r = 0; r < 4; ++r) {
      float c0 = acc[mt][0][r] + brv0;
      float c1 = acc[mt][1][r] + brv1;
      // pass 1: max with lowest-index tiebreak
      float va = (c0 >= c1) ? c0 : c1;
      int ia = (c0 >= c1) ? l15 : 16 + l15;
#pragma unroll
      for (int off = 1; off < 16; off <<= 1) {
        float ov = __shfl_xor(va, off);
        int oi = __shfl_xor(ia, off);
        if (ov > va || (ov == va && oi < ia)) { va = ov; ia = oi; }
      }
      float v1 = va; int i1 = ia;
      // pass 2
      float d0 = (i1 == l15) ? NINF : c0;
      float d1 = (i1 == 16 + l15) ? NINF : c1;
      float vb = (d0 >= d1) ? d0 : d1;
      int ib = (d0 >= d1) ? l15 : 16 + l15;
#pragma unroll
      for (int off = 1; off < 16; off <<= 1) {
        float ov = __shfl_xor(vb, off);
        int oi = __shfl_xor(ib, off);
        if (ov > vb || (ov == vb && oi < ib)) { vb = ov; ib = oi; }
      }
      float v2 = vb; int i2 = ib;
      // pass 3: third-largest value (for suspect detection)
      float e0 = (i1 == l15 || i2 == l15) ? NINF : c0;
      float e1 = (i1 == 16 + l15 || i2 == 16 + l15) ? NINF : c1;
      float vc = (e0 >= e1) ? e0 : e1;
#pragma unroll
      for (int off = 1; off < 16; off <<= 1) {
        float ov = __shfl_xor(vc, off);
        vc = (ov > vc) ? ov : vc;
      }
      // softmax denominator
      float s = __expf(c0 - v1) + __expf(c1 - v1);
#pragma unroll
      for (int off = 1; off < 16; off <<= 1) s += __shfl_xor(s, off);
      if (l15 == 0) {
        int n = tok0 + mt * 16 + quad * 4 + r;
        int2 ti; ti.x = i1; ti.y = i2;
        float2 tv; tv.x = 1.0f / s; tv.y = __expf(v2 - v1) / s;
        ((int2*)top_idx)[n] = ti;
        ((float2*)top_val)[n] = tv;
        if (v2 - vc < 2e-3f) {
          int sidx = atomicAdd(n_suspect, 1);
          suspects[sidx] = n;
        }
      }
    }
  }
}

// ---------------- fp64 re-resolution of near-tie tokens ----------------
__global__ __launch_bounds__(256) void k_router_fix(
    const float* __restrict__ x, const double* __restrict__ wrt64,
    const float* __restrict__ br, const int* __restrict__ suspects,
    const int* __restrict__ n_suspect, int* __restrict__ top_idx,
    float* __restrict__ top_val) {
  int t = threadIdx.x;
  int lt = t & 31;
  int gid = blockIdx.x * 8 + (t >> 5);
  int cnt = *n_suspect;
  const double* wcol = wrt64 + lt * DIM;
  for (int s = gid; s < cnt; s += 128 * 8) {
    int n = suspects[s];
    const float* xr = x + (size_t)n * DIM;
    double a = 0.0;
#pragma unroll 8
    for (int d = 0; d < DIM; ++d) a = fma((double)xr[d], wcol[d], a);
    double lv = a + (double)br[lt];

    double v1 = lv; int i1 = lt;
#pragma unroll
    for (int off = 16; off > 0; off >>= 1) {
      double ov = __shfl_xor(v1, off, 32);
      int oi = __shfl_xor(i1, off, 32);
      if (ov > v1 || (ov == v1 && oi < i1)) { v1 = ov; i1 = oi; }
    }
    double lv2 = (lt == i1) ? -1.0e300 : lv;
    double v2 = lv2; int i2 = lt;
#pragma unroll
    for (int off = 16; off > 0; off >>= 1) {
      double ov = __shfl_xor(v2, off, 32);
      int oi = __shfl_xor(i2, off, 32);
      if (ov > v2 || (ov == v2 && oi < i2)) { v2 = ov; i2 = oi; }
    }
    float p = expf((float)(lv - v1));
    float ssum = p;
#pragma unroll
    for (int off = 16; off > 0; off >>= 1) ssum += __shfl_xor(ssum, off, 32);
    if (lt == 0) {
      top_idx[n * 2 + 0] = i1;
      top_idx[n * 2 + 1] = i2;
      top_val[n * 2 + 0] = 1.0f / ssum;
      top_val[n * 2 + 1] = expf((float)(v2 - v1)) / ssum;
    }
  }
}

// ---------------- fallback-only: fp64 router (rounds 1-3 structure) ----------------
__global__ __launch_bounds__(256) void k_router_f64(const float* __restrict__ x,
                                                    const double* __restrict__ wrt64,
                                                    const float* __restrict__ br,
                                                    int* __restrict__ top_idx,
                                                    float* __restrict__ top_val) {
  int t = threadIdx.x;
  int lt = t & 31;
  int n = blockIdx.x * 8 + (t >> 5);
  const double* wcol = wrt64 + lt * DIM;
  const float* xr = x + (size_t)n * DIM;
  double a = 0.0;
#pragma unroll 8
  for (int d = 0; d < DIM; ++d) a = fma((double)xr[d], wcol[d], a);
  double lv = a + (double)br[lt];
  double v1 = lv; int i1 = lt;
#pragma unroll
  for (int off = 16; off > 0; off >>= 1) {
    double ov = __shfl_xor(v1, off, 32);
    int oi = __shfl_xor(i1, off, 32);
    if (ov > v1 || (ov == v1 && oi < i1)) { v1 = ov; i1 = oi; }
  }
  double lv2 = (lt == i1) ? -1.0e300 : lv;
  double v2 = lv2; int i2 = lt;
#pragma unroll
  for (int off = 16; off > 0; off >>= 1) {
    double ov = __shfl_xor(v2, off, 32);
    int oi = __shfl_xor(i2, off, 32);
    if (ov > v2 || (ov == v2 && oi < i2)) { v2 = ov; i2 = oi; }
  }
  float p = expf((float)(lv - v1));
  float ssum = p;
#pragma unroll
  for (int off = 16; off > 0; off >>= 1) ssum += __shfl_xor(ssum, off, 32);
  if (lt == 0) {
    top_idx[n * 2 + 0] = i1;
    top_idx[n * 2 + 1] = i2;
    top_val[n * 2 + 0] = 1.0f / ssum;
    top_val[n * 2 + 1] = expf((float)(v2 - v1)) / ssum;
  }
}

// ---------------- histogram: counts + importance ----------------
__global__ void k_hist(const int* __restrict__ top_idx, const float* __restrict__ top_val,
                       int* __restrict__ counts, float* __restrict__ importance) {
  __shared__ int hc[NE];
  __shared__ float hf[NE];
  int t = threadIdx.x;
  if (t < NE) { hc[t] = 0; hf[t] = 0.f; }
  __syncthreads();
#pragma unroll
  for (int j = 0; j < 2; ++j) {
    int i = (j * 256 + blockIdx.x) * 256 + t;
    int e = top_idx[i];
    atomicAdd(&hc[e], 1);
    atomicAdd(&hf[e], top_val[i]);
  }
  __syncthreads();
  if (t < NE) {
    atomicAdd(&counts[t], hc[t]);
    atomicAdd(&importance[t], hf[t]);
  }
}

// ---------------- padded scan + load-balancing loss ----------------
__global__ void k_scan_loss(const int* __restrict__ counts, const float* __restrict__ importance,
                            int* __restrict__ offsets, float* __restrict__ out_loss) {
  int t = threadIdx.x;
  if (t < NE) {
    int pc = (counts[t] + 63) & ~63;
    int sc = pc;
#pragma unroll
    for (int off = 1; off < 32; off <<= 1) {
      int ov = __shfl_up(sc, off, 32);
      if (t >= off) sc += ov;
    }
    offsets[t] = sc - pc;
    if (t == NE - 1) offsets[NE] = sc;

    float imp = importance[t];
    float ssum = imp;
#pragma unroll
    for (int off = 16; off > 0; off >>= 1) ssum += __shfl_xor(ssum, off, 32);
    float mean = ssum / 32.0f;
    float dlt = imp - mean;
    float v = dlt * dlt;
#pragma unroll
    for (int off = 16; off > 0; off >>= 1) v += __shfl_xor(v, off, 32);
    float var = v / 31.0f;
    if (t == 0) *out_loss = var / (mean * mean + 1e-9f);
  }
}

// ---------------- scatter into per-expert lists (+ inverse map) ----------------
__global__ void k_scatter(const int* __restrict__ top_idx, const float* __restrict__ top_val,
                          const int* __restrict__ offsets, int* __restrict__ cursors,
                          int* __restrict__ perm, float* __restrict__ gatev,
                          int* __restrict__ inv) {
  __shared__ int hist[NE], base[NE], cur[NE];
  int t = threadIdx.x;
  if (t < NE) { hist[t] = 0; cur[t] = 0; }
  __syncthreads();
#pragma unroll
  for (int j = 0; j < 4; ++j) {
    int i = blockIdx.x * 1024 + j * 256 + t;
    atomicAdd(&hist[top_idx[i]], 1);
  }
  __syncthreads();
  if (t < NE) base[t] = atomicAdd(&cursors[t], hist[t]);
  __syncthreads();
#pragma unroll
  for (int j = 0; j < 4; ++j) {
    int i = blockIdx.x * 1024 + j * 256 + t;
    int e = top_idx[i];
    int p = atomicAdd(&cur[e], 1);
    int pos = offsets[e] + base[e] + p;
    perm[pos] = i >> 1;
    gatev[pos] = top_val[i];
    inv[i] = pos;
  }
}

// ---------------- fused expert GEMM: 64 tokens x 1 expert per block ----------------
template <int YB>
__global__ __launch_bounds__(256, 2) void k_expert(
    const float* __restrict__ x, const unsigned short* __restrict__ w1t,
    const unsigned short* __restrict__ w2t, const float* __restrict__ b1,
    const float* __restrict__ b2, const int* __restrict__ offsets,
    const int* __restrict__ counts, const int* __restrict__ perm,
    const float* __restrict__ gatev, unsigned short* __restrict__ ybuf,
    float* __restrict__ out) {
  __shared__ __align__(16) unsigned char smem[49152];
  unsigned char* xa = smem;                 // 16 KB: [c 0..15][row 0..63][16B]
  unsigned char* ha = smem + 16384;         // 32 KB: [c 0..31][row 0..63][16B]

  int slot0 = blockIdx.x * 64;
  if (slot0 >= offsets[NE]) return;
  int e = 0;
#pragma unroll
  for (int i = 1; i < NE; ++i)
    if (slot0 >= offsets[i]) e = i;
  int cnt = counts[e];
  int local0 = slot0 - offsets[e];
  int nvalid = min(64, cnt - local0);

  int t = threadIdx.x;
  int w = t >> 6;
  int l = t & 63;
  int quad = l >> 4;
  int l15 = l & 15;

  const unsigned short* w1e = w1t + (size_t)e * DIM * HID;
  bf16x8 w1f[4][4];
#pragma unroll
  for (int kc = 0; kc < 4; ++kc)
#pragma unroll
    for (int jt = 0; jt < 4; ++jt)
      w1f[kc][jt] = *(const bf16x8*)(w1e + kc * 8192 + (w * 64 + jt * 16 + l15) * 32 + quad * 8);

  {
    int r = t & 63;
    int half = t >> 6;
    unsigned pk[16];
    if (r < nvalid) {
      int token = perm[slot0 + r];
      const float* src = x + (size_t)token * DIM + half * 32;
#pragma unroll
      for (int q = 0; q < 8; ++q) {
        float4 v = ((const float4*)src)[q];
        pk[q * 2 + 0] = (unsigned)f2bf(v.x) | ((unsigned)f2bf(v.y) << 16);
        pk[q * 2 + 1] = (unsigned)f2bf(v.z) | ((unsigned)f2bf(v.w) << 16);
      }
    } else {
#pragma unroll
      for (int q = 0; q < 16; ++q) pk[q] = 0u;
    }
#pragma unroll
    for (int cc = 0; cc < 4; ++cc) {
      uint4 u;
      u.x = pk[cc * 4 + 0]; u.y = pk[cc * 4 + 1]; u.z = pk[cc * 4 + 2]; u.w = pk[cc * 4 + 3];
      *(uint4*)(xa + (half * 4 + cc) * 1024 + r * 16) = u;
    }
  }
  __syncthreads();

  f32x4 acc[4][4];
#pragma unroll
  for (int a = 0; a < 4; ++a)
#pragma unroll
    for (int b = 0; b < 4; ++b) {
      f32x4 z = {0.f, 0.f, 0.f, 0.f};
      acc[a][b] = z;
    }
#pragma unroll
  for (int kc = 0; kc < 4; ++kc) {
    bf16x8 af[4];
#pragma unroll
    for (int rt = 0; rt < 4; ++rt)
      af[rt] = *(const bf16x8*)(xa + (kc * 4 + quad) * 1024 + (rt * 16 + l15) * 16);
#pragma unroll
    for (int rt = 0; rt < 4; ++rt)
#pragma unroll
      for (int jt = 0; jt < 4; ++jt)
        acc[rt][jt] = __builtin_amdgcn_mfma_f32_16x16x32_bf16(af[rt], w1f[kc][jt], acc[rt][jt], 0, 0, 0);
  }

  const unsigned short* w2e = w2t + (size_t)e * HID * DIM;
  bf16x8 w2f[8][2];
#pragma unroll
  for (int hc = 0; hc < 8; ++hc)
#pragma unroll
    for (int jt = 0; jt < 2; ++jt)
      w2f[hc][jt] = *(const bf16x8*)(w2e + hc * 4096 + (w * 32 + jt * 16 + l15) * 32 + quad * 8);

  const float* b1e = b1 + e * HID;
#pragma unroll
  for (int jt = 0; jt < 4; ++jt) {
    int col = w * 64 + jt * 16 + l15;
    float b1v = b1e[col];
    int c = col >> 3;
    int byteoff = (col & 7) * 2;
#pragma unroll
    for (int rt = 0; rt < 4; ++rt) {
#pragma unroll
      for (int r = 0; r < 4; ++r) {
        int tokrow = rt * 16 + quad * 4 + r;
        float v = acc[rt][jt][r] + b1v;
        v = v > 0.f ? v : 0.f;
        *(unsigned short*)(ha + c * 1024 + tokrow * 16 + byteoff) = f2bf(v);
      }
    }
  }
  __syncthreads();

  f32x4 accc[4][2];
#pragma unroll
  for (int a = 0; a < 4; ++a)
#pragma unroll
    for (int b = 0; b < 2; ++b) {
      f32x4 z = {0.f, 0.f, 0.f, 0.f};
      accc[a][b] = z;
    }
#pragma unroll
  for (int hc = 0; hc < 8; ++hc) {
    bf16x8 ah[4];
#pragma unroll
    for (int rt = 0; rt < 4; ++rt)
      ah[rt] = *(const bf16x8*)(ha + (hc * 4 + quad) * 1024 + (rt * 16 + l15) * 16);
#pragma unroll
    for (int rt = 0; rt < 4; ++rt)
#pragma unroll
      for (int jt = 0; jt < 2; ++jt)
        accc[rt][jt] = __builtin_amdgcn_mfma_f32_16x16x32_bf16(ah[rt], w2f[hc][jt], accc[rt][jt], 0, 0, 0);
  }

  int dbase = w * 32;
  float b2v0 = b2[e * DIM + dbase + l15];
  float b2v1 = b2[e * DIM + dbase + 16 + l15];
#pragma unroll
  for (int rt = 0; rt < 4; ++rt) {
#pragma unroll
    for (int r = 0; r < 4; ++r) {
      int tokrow = rt * 16 + quad * 4 + r;
      if (tokrow < nvalid) {
        int pos = slot0 + tokrow;
        float g = gatev[pos];
        if (YB) {
          unsigned short* yrow = ybuf + (size_t)pos * DIM + dbase;
          yrow[l15] = f2bf(g * (accc[rt][0][r] + b2v0));
          yrow[16 + l15] = f2bf(g * (accc[rt][1][r] + b2v1));
        } else {
          int token = perm[pos];
          float* orow = out + (size_t)token * DIM + dbase;
          atomicAdd(&orow[l15], g * (accc[rt][0][r] + b2v0));
          atomicAdd(&orow[16 + l15], g * (accc[rt][1][r] + b2v1));
        }
      }
    }
  }
}

// ---------------- combine: out[n] = y[inv[2n]] + y[inv[2n+1]] ----------------
__global__ __launch_bounds__(256) void k_combine(const unsigned short* __restrict__ ybuf,
                                                 const int* __restrict__ inv,
                                                 float* __restrict__ out) {
  int t = threadIdx.x;
  int n = blockIdx.x * 16 + (t >> 4);
  int lane = t & 15;
  int p0 = inv[n * 2 + 0];
  int p1 = inv[n * 2 + 1];
  uint4 a = *((const uint4*)(ybuf + (size_t)p0 * DIM) + lane);
  uint4 b = *((const uint4*)(ybuf + (size_t)p1 * DIM) + lane);
  unsigned av[4] = {a.x, a.y, a.z, a.w}, bv[4] = {b.x, b.y, b.z, b.w};
  float r[8];
#pragma unroll
  for (int q = 0; q < 4; ++q) {
    r[q * 2 + 0] = bf2f(av[q] & 0xffffu) + bf2f(bv[q] & 0xffffu);
    r[q * 2 + 1] = bf2f(av[q] >> 16) + bf2f(bv[q] >> 16);
  }
  float* orow = out + (size_t)n * DIM + lane * 8;
  float4 w0 = {r[0], r[1], r[2], r[3]}, w1 = {r[4], r[5], r[6], r[7]};
  ((float4*)orow)[0] = w0;
  ((float4*)orow)[1] = w1;
}

extern "C" void kernel_launch(void* const* d_in, const int* in_sizes, int n_in,
                              void* d_out, int out_size, void* d_ws, size_t ws_size,
                              hipStream_t stream) {
  const float* x  = (const float*)d_in[0];
  const float* W1 = (const float*)d_in[1];
  const float* b1 = (const float*)d_in[2];
  const float* W2 = (const float*)d_in[3];
  const float* b2 = (const float*)d_in[4];
  const float* Wr = (const float*)d_in[5];
  const float* br = (const float*)d_in[6];
  float* out = (float*)d_out;

  char* ws = (char*)d_ws;
  float* importance   = (float*)(ws + 0);       // 32 f
  int*   counts       = (int*)(ws + 128);       // 32 i
  int*   cursors      = (int*)(ws + 256);       // 32 i
  int*   offsets      = (int*)(ws + 384);       // 33 i
  int*   top_idx      = (int*)(ws + 1024);              // 131072 i
  float* top_val      = (float*)(ws + 525312);          // 131072 f
  int*   perm         = (int*)(ws + 1049600);           // 133120 i
  float* gatev        = (float*)(ws + 1582080);         // 133120 f
  int*   inv          = (int*)(ws + 2114560);           // 131072 i -> 2638848
  unsigned short* w1t = (unsigned short*)(ws + 2638848);            // 2 MB -> 4736000
  unsigned short* w2t = (unsigned short*)(ws + 4736000);            // 2 MB -> 6833152
  unsigned short* ybuf = (unsigned short*)(ws + 6833152);           // 34078720 -> 40911872
  double* wrt64 = (double*)(ws + 6833152);            // 32 KB, aliases ybuf head (dead before k_expert)
  unsigned short* wrb = (unsigned short*)(ws + 6833152 + 32768);  // 32 KB, aliases ybuf (dead before k_expert)
  int* suspects = (int*)(ws + 40911872);              // 65536 i -> 41174016
  int* n_suspect = (int*)(ws + 41174016);             // -> 41174144
  const size_t NEEDED = 41174144;
  bool use_ybuf = ws_size >= NEEDED;

  hipLaunchKernelGGL(k_weights, dim3(513), dim3(256), 0, stream, W1, W2, Wr, w1t, w2t, wrt64,
                     wrb, (float*)ws, n_suspect);
  if (use_ybuf) {
    hipLaunchKernelGGL(k_router, dim3(256), dim3(256), 0, stream, x, wrb, br, top_idx, top_val,
                       suspects, n_suspect);
    hipLaunchKernelGGL(k_router_fix, dim3(128), dim3(256), 0, stream, x, wrt64, br, suspects,
                       n_suspect, top_idx, top_val);
  } else {
    hipLaunchKernelGGL(k_router_f64, dim3(8192), dim3(256), 0, stream, x, wrt64, br, top_idx,
                       top_val);
  }
  hipLaunchKernelGGL(k_hist, dim3(256), dim3(256), 0, stream, top_idx, top_val, counts, importance);
  hipLaunchKernelGGL(k_scan_loss, dim3(1), dim3(64), 0, stream, counts, importance, offsets,
                     out + (size_t)N_TOK * DIM);
  hipLaunchKernelGGL(k_scatter, dim3(128), dim3(256), 0, stream, top_idx, top_val, offsets,
                     cursors, perm, gatev, inv);
  if (use_ybuf) {
    hipLaunchKernelGGL((k_expert<1>), dim3(2080), dim3(256), 0, stream, x, w1t, w2t, b1, b2,
                       offsets, counts, perm, gatev, ybuf, out);
    hipLaunchKernelGGL(k_combine, dim3(4096), dim3(256), 0, stream, ybuf, inv, out);
  } else {
    hipLaunchKernelGGL(k_zero_out, dim3(4096), dim3(256), 0, stream, out);
    hipLaunchKernelGGL((k_expert<0>), dim3(2080), dim3(256), 0, stream, x, w1t, w2t, b1, b2,
                       offsets, counts, perm, gatev, ybuf, out);
  }
}